// Round 5
// baseline (465.945 us; speedup 1.0000x reference)
//
#include <hip/hip_runtime.h>

#define SEQ 1024
#define NT 512   // 8 waves; wave w owns gate-preact cols [16w,16w+16) for r,z,n

typedef _Float16 half8 __attribute__((ext_vector_type(8)));  // 4 VGPRs
typedef float f32x4 __attribute__((ext_vector_type(4)));     // MFMA 16x16 accum

// h buffer layout (halfwords): [buf][0..127]=h_hi, [buf][160..287]=h_lo.
// lo offset 160 hw = 80 words = bank shift 16 -> a wave's 8 distinct A-read
// addresses (hl in {0,1} x quad in {0..3}) cover all 32 banks exactly once.
#define LO_OFF 160
#define HBUF 320

#define NLOG2E  (-1.4426950408889634f)   // -log2(e): sigmoid via exp2
#define N2LOG2E (-2.8853900817779268f)   // -2*log2(e): tanh via exp2

__global__ __launch_bounds__(NT, 2)
void gru_kernel(const float* __restrict__ x,     // [B, S, 1]
                const float* __restrict__ w_ih,  // [3H, 1]
                const float* __restrict__ w_hh,  // [3H, H]
                const float* __restrict__ b_ih,  // [3H]
                const float* __restrict__ b_hh,  // [3H]
                const float* __restrict__ w_fc,  // [1, H]
                const float* __restrict__ b_fc,  // [1]
                float* __restrict__ out)         // [B, 1]
{
  __shared__ float xs[SEQ + 2];
  __shared__ __align__(16) _Float16 hs[2][HBUF];
  __shared__ float red[8];

  const int t = threadIdx.x;
  const int b = blockIdx.x;
  const int w = t >> 6;          // wave 0..7
  const int L = t & 63;          // lane
  const int n = L & 15;          // MFMA col (unit in tile) == A-row m
  const int quad = L >> 4;       // k-slice / C-row group
  const int u = 16 * w + n;      // hidden unit
  const int hl = n & 1;          // A-row parity: even rows = h_hi, odd = h_lo
  const bool boost = (w & 1) == 0;  // parity-skew: even waves win arbitration

  // stage x[b,:] (coalesced); pad 2 zeros for the register prefetch
  const float* xrow = x + (size_t)b * SEQ;
  for (int i = t; i < SEQ + 2; i += NT) xs[i] = (i < SEQ) ? xrow[i] : 0.f;
  if (t < HBUF) hs[0][t] = (_Float16)0.f;

  // B fragments (persistent, fp16), pre-scaled so gate preacts come out of the
  // MFMA already multiplied by -log2e (r,z) / -2log2e (n): exp2 directly.
  half8 Bw[3][4];
#pragma unroll
  for (int g = 0; g < 3; ++g) {
    const float sc = (g == 2) ? N2LOG2E : NLOG2E;
    const float* row = w_hh + (size_t)(g * 128 + u) * 128;
#pragma unroll
    for (int kt = 0; kt < 4; ++kt) {
      union { _Float16 s[8]; half8 v; } tmp;
#pragma unroll
      for (int i = 0; i < 8; ++i)
        tmp.s[i] = (_Float16)(row[kt * 32 + quad * 8 + i] * sc);
      Bw[g][kt] = tmp.v;
    }
  }
  // pre-scaled per-unit scalars (seeds fold input preact + both biases)
  const float bcr = NLOG2E * (b_ih[u] + b_hh[u]);
  const float bcz = NLOG2E * (b_ih[128 + u] + b_hh[128 + u]);
  const float bin_ = N2LOG2E * b_ih[256 + u];
  const float bhn  = N2LOG2E * b_hh[256 + u];
  const float wir = NLOG2E * w_ih[u];
  const float wiz = NLOG2E * w_ih[128 + u];
  const float win = N2LOG2E * w_ih[256 + u];

  // per-lane A-read base (halfwords): parity-selected hi/lo bank group
  const int abase = hl * LO_OFF + quad * 8;

  float hprev = 0.f;   // h[u], replicated across quads (identical math)

  // Persistent accumulators. Only regs [0],[1] are read (reg0 = even C-row ->
  // hi-dot, reg1 = odd C-row -> lo-dot, row = 4*quad + reg). Regs [2],[3]
  // accumulate unread bounded garbage across steps.
  f32x4 ar = {0.f, 0.f, 0.f, 0.f};
  f32x4 az = {0.f, 0.f, 0.f, 0.f};
  f32x4 an = {0.f, 0.f, 0.f, 0.f};

  __syncthreads();

#define MF(A, B, C) C = __builtin_amdgcn_mfma_f32_16x16x32_f16(A, B, C, 0, 0, 0)

  // One step. Gate order r, z, n (n LAST): r,z sigmoids + z*h blend-prep
  // overlap the n-gate MFMAs; post-last-MFMA serial chain is ~10 ops.
  // Even waves run at prio 1 through dots+tail: they drain their MFMAs first
  // and execute their tails while odd waves' MFMAs keep the matrix pipe fed.
#define STEP(RD, WR, XT)                                                       \
  {                                                                            \
    const float xt = (XT);                                                     \
    if (boost) __builtin_amdgcn_s_setprio(1);                                  \
    half8 A[4];                                                                \
    _Pragma("unroll")                                                          \
    for (int kt = 0; kt < 4; ++kt)                                             \
      A[kt] = *(const half8*)&hs[RD][abase + kt * 32];                         \
    ar[0] = fmaf(xt, wir, bcr); ar[1] = 0.f;                                   \
    az[0] = fmaf(xt, wiz, bcz); az[1] = 0.f;                                   \
    an[0] = bhn;                an[1] = 0.f;                                   \
    const float in_s = fmaf(xt, win, bin_);                                    \
    MF(A[0], Bw[0][0], ar); MF(A[1], Bw[0][1], ar);                            \
    MF(A[2], Bw[0][2], ar); MF(A[3], Bw[0][3], ar);                            \
    MF(A[0], Bw[1][0], az); MF(A[1], Bw[1][1], az);                            \
    MF(A[2], Bw[1][2], az); MF(A[3], Bw[1][3], az);                            \
    MF(A[0], Bw[2][0], an); MF(A[1], Bw[2][1], an);                            \
    MF(A[2], Bw[2][2], an); MF(A[3], Bw[2][3], an);                            \
    const float r = __builtin_amdgcn_rcpf(                                     \
        1.f + __builtin_amdgcn_exp2f(ar[0] + ar[1]));                          \
    const float z = __builtin_amdgcn_rcpf(                                     \
        1.f + __builtin_amdgcn_exp2f(az[0] + az[1]));                          \
    const float zh = z * hprev;                                                \
    const float omz = 1.f - z;                                                 \
    const float e = __builtin_amdgcn_exp2f(fmaf(r, an[0] + an[1], in_s));      \
    const float nn = (1.f - e) * __builtin_amdgcn_rcpf(1.f + e);               \
    hprev = fmaf(omz, nn, zh);                                                 \
    const _Float16 hih = (_Float16)hprev;                                      \
    if (quad == 0) hs[WR][u] = hih;                                            \
    if (quad == 1) hs[WR][LO_OFF + u] = (_Float16)(hprev - (float)hih);        \
    if (boost) __builtin_amdgcn_s_setprio(0);                                  \
    __syncthreads();                                                           \
  }

  float x0 = xs[0], x1 = xs[1];
  for (int s = 0; s < SEQ; s += 2) {
    const float xa = xs[s + 2], xb = xs[s + 3];  // LDS prefetch, next iter
    STEP(0, 1, x0);
    STEP(1, 0, x1);
    x0 = xa;
    x1 = xb;
  }
#undef STEP
#undef MF

  // epilogue: out[b] = relu(h_T) . w_fc + b_fc
  float v = (quad == 0) ? fmaxf(hprev, 0.f) * w_fc[u] : 0.f;
#pragma unroll
  for (int off = 1; off < 64; off <<= 1) v += __shfl_xor(v, off);
  if (L == 0) red[w] = v;
  __syncthreads();
  if (t == 0) {
    float sum = 0.f;
#pragma unroll
    for (int k = 0; k < 8; ++k) sum += red[k];
    out[b] = sum + b_fc[0];
  }
}

extern "C" void kernel_launch(void* const* d_in, const int* in_sizes, int n_in,
                              void* d_out, int out_size, void* d_ws, size_t ws_size,
                              hipStream_t stream) {
  const float* x    = (const float*)d_in[0];
  const float* w_ih = (const float*)d_in[1];
  const float* w_hh = (const float*)d_in[2];
  const float* b_ih = (const float*)d_in[3];
  const float* b_hh = (const float*)d_in[4];
  const float* w_fc = (const float*)d_in[5];
  const float* b_fc = (const float*)d_in[6];
  gru_kernel<<<256, NT, 0, stream>>>(x, w_ih, w_hh, b_ih, b_hh, w_fc, b_fc,
                                     (float*)d_out);
}

// Round 6
// 464.826 us; speedup vs baseline: 1.0024x; 1.0024x over previous
//
#include <hip/hip_runtime.h>

#define SEQ 1024
#define NT 512   // 8 waves; wave w owns gate-preact cols [16w,16w+16) for r,z,n

typedef _Float16 half8 __attribute__((ext_vector_type(8)));  // 4 VGPRs
typedef float f32x4 __attribute__((ext_vector_type(4)));     // MFMA f32 accum
typedef int   int4v __attribute__((ext_vector_type(4)));     // MFMA i8 frags/accum

// f16 h buffer (halfwords): [buf][0..127]=h_hi, [buf][160..287]=h_lo.
// lo offset 160 hw = bank shift 16 -> wave's 8 A-read addrs cover 32 banks.
#define LO_OFF 160
#define HBUF 320
// i8 h buffer (bytes): hi8 at [0..127] (banks 0-15), lo8 at [192..319]
// (banks 16-31): the b128 A-reads' 8 addresses are bank-disjoint.
#define QLO 192
#define QBUF 320

#define NLOG2E  (-1.4426950408889634f)   // -log2(e): sigmoid via exp2
#define N2LOG2E (-2.8853900817779268f)   // -2*log2(e): tanh via exp2

__global__ __launch_bounds__(NT, 2)
void gru_kernel(const float* __restrict__ x,     // [B, S, 1]
                const float* __restrict__ w_ih,  // [3H, 1]
                const float* __restrict__ w_hh,  // [3H, H]
                const float* __restrict__ b_ih,  // [3H]
                const float* __restrict__ b_hh,  // [3H]
                const float* __restrict__ w_fc,  // [1, H]
                const float* __restrict__ b_fc,  // [1]
                float* __restrict__ out)         // [B, 1]
{
  __shared__ float xs[SEQ + 2];
  __shared__ __align__(16) _Float16 hs[2][HBUF];
  __shared__ __align__(16) char hq[2][QBUF];
  __shared__ float red[8];

  const int t = threadIdx.x;
  const int b = blockIdx.x;
  const int w = t >> 6;          // wave 0..7
  const int L = t & 63;          // lane
  const int n = L & 15;          // MFMA col (unit in tile) == A-row m
  const int quad = L >> 4;       // k-slice / C-row group
  const int u = 16 * w + n;      // hidden unit
  const int hl = n & 1;          // A-row parity: even rows = hi, odd = lo

  // stage x[b,:] (coalesced); pad 2 zeros for the register prefetch
  const float* xrow = x + (size_t)b * SEQ;
  for (int i = t; i < SEQ + 2; i += NT) xs[i] = (i < SEQ) ? xrow[i] : 0.f;
  if (t < HBUF) hs[0][t] = (_Float16)0.f;
  if (t < QBUF) hq[0][t] = 0;

  // n-gate B fragments (f16, persistent), pre-scaled by -2log2e so the tanh
  // argument comes out of the MFMA ready for exp2.
  half8 Bwn[4];
  {
    const float* row = w_hh + (size_t)(256 + u) * 128;
#pragma unroll
    for (int kt = 0; kt < 4; ++kt) {
      union { _Float16 s[8]; half8 v; } tmp;
#pragma unroll
      for (int i = 0; i < 8; ++i)
        tmp.s[i] = (_Float16)(row[kt * 32 + quad * 8 + i] * N2LOG2E);
      Bwn[kt] = tmp.v;
    }
  }

  // r,z B fragments: int8 with per-row scale (126/rowmax). Lane (n,quad)
  // holds B[k=quad*16+i][col n] for kt in {0,1} (K=64 each -> K=128 total).
  // kRec folds reconstruction 1/(127*Sw) and the -log2e sigmoid prescale.
  int4v Wq[2][2];
  float kRec[2];
#pragma unroll
  for (int g = 0; g < 2; ++g) {
    const float* row = w_hh + (size_t)(g * 128 + u) * 128;
    float wv[32];
    float m = 0.f;
#pragma unroll
    for (int kt = 0; kt < 2; ++kt)
#pragma unroll
      for (int i = 0; i < 16; ++i) {
        const float v = row[kt * 64 + quad * 16 + i];
        wv[kt * 16 + i] = v;
        m = fmaxf(m, fabsf(v));
      }
    m = fmaxf(m, __shfl_xor(m, 16));   // row max across the 4 quads
    m = fmaxf(m, __shfl_xor(m, 32));
    const float Sw = 126.f / m;
#pragma unroll
    for (int kt = 0; kt < 2; ++kt) {
      int p[4] = {0, 0, 0, 0};
#pragma unroll
      for (int i = 0; i < 16; ++i) {
        const int q = __float2int_rn(wv[kt * 16 + i] * Sw);
        p[i >> 2] |= (q & 255) << (8 * (i & 3));
      }
      const int4v pv = {p[0], p[1], p[2], p[3]};
      Wq[g][kt] = pv;
    }
    kRec[g] = NLOG2E * m / (127.f * 126.f);
  }

  // pre-scaled per-unit scalars (input preact + both biases folded)
  const float bcr = NLOG2E * (b_ih[u] + b_hh[u]);
  const float bcz = NLOG2E * (b_ih[128 + u] + b_hh[128 + u]);
  const float bin_ = N2LOG2E * b_ih[256 + u];
  const float bhn  = N2LOG2E * b_hh[256 + u];
  const float wir = NLOG2E * w_ih[u];
  const float wiz = NLOG2E * w_ih[128 + u];
  const float win = N2LOG2E * w_ih[256 + u];

  // per-lane A-read bases: f16 (halfwords) and i8 (bytes)
  const int abase = hl * LO_OFF + quad * 8;
  const int ib    = (hl ? QLO : 0) + quad * 16;

  float hprev = 0.f;   // h[u], replicated across quads (identical math)

  // Persistent accumulators; only regs [0],[1] read (reg0 = even C-row =
  // hi-dot, reg1 = odd C-row = lo-dot; row = 4*quad + reg). f32 regs [2],[3]
  // hold unread bounded garbage; i32 regs [2],[3] wrap harmlessly.
  f32x4 an = {0.f, 0.f, 0.f, 0.f};
  int4v cr = {0, 0, 0, 0};
  int4v cz = {0, 0, 0, 0};

  __syncthreads();

#define MF(A, B, C) C = __builtin_amdgcn_mfma_f32_16x16x32_f16(A, B, C, 0, 0, 0)
#define MI(A, B, C) C = __builtin_amdgcn_mfma_i32_16x16x64_i8(A, B, C, 0, 0, 0)

  // One step. i8 r,z MFMAs first (short, r needed by n's tanh); f16 n-chain
  // last so r's sigmoid overlaps its issue. Post-MFMA chain ~12 ops.
#define STEP(RD, WR, XT)                                                       \
  {                                                                            \
    const float xt = (XT);                                                     \
    const int4v Ai0 = *(const int4v*)&hq[RD][ib];                              \
    const int4v Ai1 = *(const int4v*)&hq[RD][ib + 64];                         \
    half8 A[4];                                                                \
    _Pragma("unroll")                                                          \
    for (int kt = 0; kt < 4; ++kt)                                             \
      A[kt] = *(const half8*)&hs[RD][abase + kt * 32];                         \
    cr[0] = 0; cr[1] = 0;                                                      \
    cz[0] = 0; cz[1] = 0;                                                      \
    an[0] = bhn; an[1] = 0.f;                                                  \
    const float in_s = fmaf(xt, win, bin_);                                    \
    const float sr = fmaf(xt, wir, bcr);                                       \
    const float sz = fmaf(xt, wiz, bcz);                                       \
    MI(Ai0, Wq[0][0], cr); MI(Ai0, Wq[1][0], cz);                              \
    MI(Ai1, Wq[0][1], cr); MI(Ai1, Wq[1][1], cz);                              \
    MF(A[0], Bwn[0], an); MF(A[1], Bwn[1], an);                                \
    MF(A[2], Bwn[2], an); MF(A[3], Bwn[3], an);                                \
    const float crf = fmaf((float)cr[1], 0.0078125f, (float)cr[0]);            \
    const float r = __builtin_amdgcn_rcpf(                                     \
        1.f + __builtin_amdgcn_exp2f(fmaf(crf, kRec[0], sr)));                 \
    const float czf = fmaf((float)cz[1], 0.0078125f, (float)cz[0]);            \
    const float z = __builtin_amdgcn_rcpf(                                     \
        1.f + __builtin_amdgcn_exp2f(fmaf(czf, kRec[1], sz)));                 \
    const float zh = z * hprev;                                                \
    const float omz = 1.f - z;                                                 \
    const float e = __builtin_amdgcn_exp2f(fmaf(r, an[0] + an[1], in_s));      \
    const float nn = (1.f - e) * __builtin_amdgcn_rcpf(1.f + e);               \
    hprev = fmaf(omz, nn, zh);                                                 \
    const _Float16 hih = (_Float16)hprev;                                      \
    if (quad == 0) hs[WR][u] = hih;                                            \
    if (quad == 1) hs[WR][LO_OFF + u] = (_Float16)(hprev - (float)hih);        \
    const int hi8 = __float2int_rn(hprev * 127.f);                             \
    const float resid = fmaf((float)hi8, -0.0078740157480315f, hprev);         \
    const int lo8 = __float2int_rn(resid * 16256.f);                           \
    if (quad == 2) hq[WR][u] = (char)hi8;                                      \
    if (quad == 3) hq[WR][QLO + u] = (char)lo8;                                \
    __syncthreads();                                                           \
  }

  float x0 = xs[0], x1 = xs[1];
  for (int s = 0; s < SEQ; s += 2) {
    const float xa = xs[s + 2], xb = xs[s + 3];  // LDS prefetch, next iter
    STEP(0, 1, x0);
    STEP(1, 0, x1);
    x0 = xa;
    x1 = xb;
  }
#undef STEP
#undef MF
#undef MI

  // epilogue: out[b] = relu(h_T) . w_fc + b_fc
  float v = (quad == 0) ? fmaxf(hprev, 0.f) * w_fc[u] : 0.f;
#pragma unroll
  for (int off = 1; off < 64; off <<= 1) v += __shfl_xor(v, off);
  if (L == 0) red[w] = v;
  __syncthreads();
  if (t == 0) {
    float sum = 0.f;
#pragma unroll
    for (int k = 0; k < 8; ++k) sum += red[k];
    out[b] = sum + b_fc[0];
  }
}

extern "C" void kernel_launch(void* const* d_in, const int* in_sizes, int n_in,
                              void* d_out, int out_size, void* d_ws, size_t ws_size,
                              hipStream_t stream) {
  const float* x    = (const float*)d_in[0];
  const float* w_ih = (const float*)d_in[1];
  const float* w_hh = (const float*)d_in[2];
  const float* b_ih = (const float*)d_in[3];
  const float* b_hh = (const float*)d_in[4];
  const float* w_fc = (const float*)d_in[5];
  const float* b_fc = (const float*)d_in[6];
  gru_kernel<<<256, NT, 0, stream>>>(x, w_ih, w_hh, b_ih, b_hh, w_fc, b_fc,
                                     (float*)d_out);
}

// Round 7
// 418.610 us; speedup vs baseline: 1.1131x; 1.1104x over previous
//
#include <hip/hip_runtime.h>

#define SEQ 1024
#define NT 512   // 8 waves; wave w owns units [16w,16w+16) for r,z,n

typedef int int4v __attribute__((ext_vector_type(4)));  // i8 MFMA frags/accum

// i8 h buffer (bytes): hi8 at [0..127], lo8 at [192..319], dump at [320..383].
// Read addrs per b128: 8 distinct (parity x quad), spanning all 32 banks once
// (PLO=192 -> word 48 -> bank 16), 8-lane broadcast each: conflict-free.
#define PLO  192
#define QBUF 384

#define NLOG2E  (-1.4426950408889634f)   // -log2(e): sigmoid via exp2
#define N2LOG2E (-2.8853900817779268f)   // -2*log2(e): tanh via exp2
#define INV254   (0.003937007874015748f)
#define INV254SQ (1.5500031000062e-5f)

__global__ __launch_bounds__(NT, 2)
void gru_kernel(const float* __restrict__ x,     // [B, S, 1]
                const float* __restrict__ w_ih,  // [3H, 1]
                const float* __restrict__ w_hh,  // [3H, H]
                const float* __restrict__ b_ih,  // [3H]
                const float* __restrict__ b_hh,  // [3H]
                const float* __restrict__ w_fc,  // [1, H]
                const float* __restrict__ b_fc,  // [1]
                float* __restrict__ out)         // [B, 1]
{
  __shared__ float xs[SEQ + 2];
  __shared__ __align__(16) char hq[2][QBUF];
  __shared__ float red[8];

  const int t = threadIdx.x;
  const int b = blockIdx.x;
  const int w = t >> 6;          // wave 0..7
  const int L = t & 63;          // lane
  const int n = L & 15;          // MFMA col (unit) == A-row
  const int quad = L >> 4;       // k-slice / C-row group
  const int u = 16 * w + n;      // hidden unit
  const int hl = n & 1;          // A-row parity: even rows = hi8, odd = lo8

  // stage x[b,:] (coalesced); pad 2 zeros for the register prefetch
  const float* xrow = x + (size_t)b * SEQ;
  for (int i = t; i < SEQ + 2; i += NT) xs[i] = (i < SEQ) ? xrow[i] : 0.f;
  if (t < QBUF) hq[0][t] = 0;

  // ---- weight quantization (one-time) ----
  // Lane (n,quad) holds W[k = kt*64 + quad*16 + i][col=n], kt in {0,1}.
  // r,z: single i8, scale 126/rowmax. n: dual i8 (Whi + Wlo/254), making the
  // n-gate weight error 1/(126*508) rel-of-rowmax (better than f16).
  int4v Wr[2], Wz[2], Wnh[2], Wnl[2];
  float kr, kz, kn;
#pragma unroll
  for (int g = 0; g < 3; ++g) {
    const float* row = w_hh + (size_t)(g * 128 + u) * 128;
    float wv[32];
    float m = 0.f;
#pragma unroll
    for (int kt = 0; kt < 2; ++kt)
#pragma unroll
      for (int i = 0; i < 16; ++i) {
        const float v = row[kt * 64 + quad * 16 + i];
        wv[kt * 16 + i] = v;
        m = fmaxf(m, fabsf(v));
      }
    m = fmaxf(m, __shfl_xor(m, 16));   // rowmax across the 4 quads
    m = fmaxf(m, __shfl_xor(m, 32));
    const float Sw = 126.f / m;
#pragma unroll
    for (int kt = 0; kt < 2; ++kt) {
      int ph[4] = {0, 0, 0, 0}, pl[4] = {0, 0, 0, 0};
#pragma unroll
      for (int i = 0; i < 16; ++i) {
        const float sv = wv[kt * 16 + i] * Sw;
        const int qh = __float2int_rn(sv);
        const int ql = __float2int_rn((sv - (float)qh) * 254.f);
        ph[i >> 2] |= (qh & 255) << (8 * (i & 3));
        pl[i >> 2] |= (ql & 255) << (8 * (i & 3));
      }
      const int4v vh = {ph[0], ph[1], ph[2], ph[3]};
      const int4v vl = {pl[0], pl[1], pl[2], pl[3]};
      if (g == 0) Wr[kt] = vh;
      else if (g == 1) Wz[kt] = vh;
      else { Wnh[kt] = vh; Wnl[kt] = vl; }
    }
    const float ksc = m / 16002.f;     // m/(126*127)
    if (g == 0) kr = NLOG2E * ksc;
    else if (g == 1) kz = NLOG2E * ksc;
    else kn = N2LOG2E * ksc;
  }

  // pre-scaled per-unit scalars (input preact + biases folded into seeds)
  const float bcr = NLOG2E * (b_ih[u] + b_hh[u]);
  const float bcz = NLOG2E * (b_ih[128 + u] + b_hh[128 + u]);
  const float bin_ = N2LOG2E * b_ih[256 + u];
  const float bhn_s = N2LOG2E * b_hh[256 + u];
  const float wir = NLOG2E * w_ih[u];
  const float wiz = NLOG2E * w_ih[128 + u];
  const float win = N2LOG2E * w_ih[256 + u];

  // per-lane A-read base (bytes) and branchless-store dump address
  const int ib = (hl ? PLO : 0) + quad * 16;
  const int dumpa = 320 + ((L & 31) << 1);

  float hprev = 0.f;   // h[u], replicated across quads (identical math)

  // Persistent i32 accumulators; only regs [0],[1] read (reg0 = even C-row =
  // hi-dot, reg1 = odd C-row = lo-dot; row = 4*quad + reg). Regs [2],[3]
  // wrap harmlessly across steps.
  int4v cr = {0, 0, 0, 0};
  int4v cz = {0, 0, 0, 0};
  int4v ca = {0, 0, 0, 0};   // n-gate, B = Whi
  int4v cb = {0, 0, 0, 0};   // n-gate, B = Wlo

  __syncthreads();

#define MI(A, B, C) C = __builtin_amdgcn_mfma_i32_16x16x64_i8(A, B, C, 0, 0, 0)

  // One step. h lives as i8 hi/lo: h*127 ~ hi8 + lo8/254 (exact i32 dots,
  // float recon). r's MFMAs first (needed by n's tanh), z last (needed only
  // at the final blend).
#define STEP(RD, WR, XT)                                                       \
  {                                                                            \
    const float xt = (XT);                                                     \
    const int4v Ai0 = *(const int4v*)&hq[RD][ib];                              \
    const int4v Ai1 = *(const int4v*)&hq[RD][ib + 64];                         \
    cr[0] = 0; cr[1] = 0;                                                      \
    cz[0] = 0; cz[1] = 0;                                                      \
    ca[0] = 0; ca[1] = 0;                                                      \
    cb[0] = 0; cb[1] = 0;                                                      \
    const float sr = fmaf(xt, wir, bcr);                                       \
    const float sz = fmaf(xt, wiz, bcz);                                       \
    const float in_s = fmaf(xt, win, bin_);                                    \
    MI(Ai0, Wr[0], cr);  MI(Ai1, Wr[1], cr);                                   \
    MI(Ai0, Wnh[0], ca); MI(Ai1, Wnh[1], ca);                                  \
    MI(Ai0, Wnl[0], cb); MI(Ai1, Wnl[1], cb);                                  \
    MI(Ai0, Wz[0], cz);  MI(Ai1, Wz[1], cz);                                   \
    const float crf = fmaf((float)cr[1], INV254, (float)cr[0]);                \
    const float r = __builtin_amdgcn_rcpf(                                     \
        1.f + __builtin_amdgcn_exp2f(fmaf(crf, kr, sr)));                      \
    const int tmid = ca[1] + cb[0];                                            \
    float nf = fmaf((float)tmid, INV254, (float)ca[0]);                        \
    nf = fmaf((float)cb[1], INV254SQ, nf);                                     \
    const float czf = fmaf((float)cz[1], INV254, (float)cz[0]);                \
    const float z = __builtin_amdgcn_rcpf(                                     \
        1.f + __builtin_amdgcn_exp2f(fmaf(czf, kz, sz)));                      \
    const float e =                                                            \
        __builtin_amdgcn_exp2f(fmaf(r, fmaf(nf, kn, bhn_s), in_s));            \
    const float nn = (1.f - e) * __builtin_amdgcn_rcpf(1.f + e);               \
    const float zh = z * hprev;                                                \
    const float omz = 1.f - z;                                                 \
    hprev = fmaf(omz, nn, zh);                                                 \
    const float hsc = hprev * 127.f;                                           \
    const int hi8 = __float2int_rn(hsc);                                       \
    const int lo8 = __float2int_rn((hsc - (float)hi8) * 254.f);                \
    int addr = (quad == 0) ? u : dumpa;                                        \
    addr = (quad == 1) ? (PLO + u) : addr;                                     \
    const int val = (quad == 1) ? lo8 : hi8;                                   \
    hq[WR][addr] = (char)val;                                                  \
    __syncthreads();                                                           \
  }

  float x0 = xs[0], x1 = xs[1];
  for (int s = 0; s < SEQ; s += 2) {
    const float xa = xs[s + 2], xb = xs[s + 3];  // LDS prefetch, next iter
    STEP(0, 1, x0);
    STEP(1, 0, x1);
    x0 = xa;
    x1 = xb;
  }
#undef STEP
#undef MI

  // epilogue: out[b] = relu(h_T) . w_fc + b_fc   (hprev is exact f32)
  float v = (quad == 0) ? fmaxf(hprev, 0.f) * w_fc[u] : 0.f;
#pragma unroll
  for (int off = 1; off < 64; off <<= 1) v += __shfl_xor(v, off);
  if (L == 0) red[w] = v;
  __syncthreads();
  if (t == 0) {
    float sum = 0.f;
#pragma unroll
    for (int k = 0; k < 8; ++k) sum += red[k];
    out[b] = sum + b_fc[0];
  }
}

extern "C" void kernel_launch(void* const* d_in, const int* in_sizes, int n_in,
                              void* d_out, int out_size, void* d_ws, size_t ws_size,
                              hipStream_t stream) {
  const float* x    = (const float*)d_in[0];
  const float* w_ih = (const float*)d_in[1];
  const float* w_hh = (const float*)d_in[2];
  const float* b_ih = (const float*)d_in[3];
  const float* b_hh = (const float*)d_in[4];
  const float* w_fc = (const float*)d_in[5];
  const float* b_fc = (const float*)d_in[6];
  gru_kernel<<<256, NT, 0, stream>>>(x, w_ih, w_hh, b_ih, b_hh, w_fc, b_fc,
                                     (float*)d_out);
}

// Round 8
// 392.066 us; speedup vs baseline: 1.1884x; 1.0677x over previous
//
#include <hip/hip_runtime.h>

#define SEQ 1024
#define NT 512   // 8 waves; wave w owns units [16w,16w+16) for r,z,n

typedef int int4v __attribute__((ext_vector_type(4)));  // i8 MFMA frags/accum

// i8 h buffer (bytes): hi8 at [0..127], lo8 at [192..319], dump at [320..383].
// Read addrs per b128: 8 distinct (parity x quad), spanning all 32 banks once
// (PLO=192 -> word 48 -> bank 16), 8-lane broadcast each: conflict-free.
#define PLO  192
#define QBUF 384

#define NLOG2E  (-1.4426950408889634f)   // -log2(e): sigmoid via exp2
#define N2LOG2E (-2.8853900817779268f)   // -2*log2(e): tanh via exp2
#define INV254   (0.003937007874015748f)
#define INV254SQ (1.5500031000062e-5f)

__global__ __launch_bounds__(NT, 2)
void gru_kernel(const float* __restrict__ x,     // [B, S, 1]
                const float* __restrict__ w_ih,  // [3H, 1]
                const float* __restrict__ w_hh,  // [3H, H]
                const float* __restrict__ b_ih,  // [3H]
                const float* __restrict__ b_hh,  // [3H]
                const float* __restrict__ w_fc,  // [1, H]
                const float* __restrict__ b_fc,  // [1]
                float* __restrict__ out)         // [B, 1]
{
  __shared__ __align__(8) float xs[SEQ + 2];
  __shared__ __align__(16) char hq[2][QBUF];
  __shared__ float red[8];

  const int t = threadIdx.x;
  const int b = blockIdx.x;
  const int w = t >> 6;          // wave 0..7
  const int L = t & 63;          // lane
  const int n = L & 15;          // MFMA col (unit) == A-row
  const int quad = L >> 4;       // k-slice / C-row group
  const int u = 16 * w + n;      // hidden unit
  const int hl = n & 1;          // A-row parity: even rows = hi8, odd = lo8

  // stage x[b,:] (coalesced); pad 2 zeros for the register prefetch
  const float* xrow = x + (size_t)b * SEQ;
  for (int i = t; i < SEQ + 2; i += NT) xs[i] = (i < SEQ) ? xrow[i] : 0.f;
  if (t < QBUF) hq[0][t] = 0;

  // ---- weight quantization (one-time) ----
  // Lane (n,quad) holds W[k = kt*64 + quad*16 + i][col=n], kt in {0,1}.
  // r,z: single i8, scale 126/rowmax. n: dual i8 (Whi + Wlo/254), making the
  // n-gate weight error 1/(126*508) rel-of-rowmax (better than f16).
  int4v Wr[2], Wz[2], Wnh[2], Wnl[2];
  float kr, kz, kn;
#pragma unroll
  for (int g = 0; g < 3; ++g) {
    const float* row = w_hh + (size_t)(g * 128 + u) * 128;
    float wv[32];
    float m = 0.f;
#pragma unroll
    for (int kt = 0; kt < 2; ++kt)
#pragma unroll
      for (int i = 0; i < 16; ++i) {
        const float v = row[kt * 64 + quad * 16 + i];
        wv[kt * 16 + i] = v;
        m = fmaxf(m, fabsf(v));
      }
    m = fmaxf(m, __shfl_xor(m, 16));   // rowmax across the 4 quads
    m = fmaxf(m, __shfl_xor(m, 32));
    const float Sw = 126.f / m;
#pragma unroll
    for (int kt = 0; kt < 2; ++kt) {
      int ph[4] = {0, 0, 0, 0}, pl[4] = {0, 0, 0, 0};
#pragma unroll
      for (int i = 0; i < 16; ++i) {
        const float sv = wv[kt * 16 + i] * Sw;
        const int qh = __float2int_rn(sv);
        const int ql = __float2int_rn((sv - (float)qh) * 254.f);
        ph[i >> 2] |= (qh & 255) << (8 * (i & 3));
        pl[i >> 2] |= (ql & 255) << (8 * (i & 3));
      }
      const int4v vh = {ph[0], ph[1], ph[2], ph[3]};
      const int4v vl = {pl[0], pl[1], pl[2], pl[3]};
      if (g == 0) Wr[kt] = vh;
      else if (g == 1) Wz[kt] = vh;
      else { Wnh[kt] = vh; Wnl[kt] = vl; }
    }
    const float ksc = m / 16002.f;     // m/(126*127)
    if (g == 0) kr = NLOG2E * ksc;
    else if (g == 1) kz = NLOG2E * ksc;
    else kn = N2LOG2E * ksc;
  }

  // pre-scaled per-unit scalars (input preact + biases folded into seeds)
  const float bcr = NLOG2E * (b_ih[u] + b_hh[u]);
  const float bcz = NLOG2E * (b_ih[128 + u] + b_hh[128 + u]);
  const float bin_ = N2LOG2E * b_ih[256 + u];
  const float bhn_s = N2LOG2E * b_hh[256 + u];
  const float wir = NLOG2E * w_ih[u];
  const float wiz = NLOG2E * w_ih[128 + u];
  const float win = N2LOG2E * w_ih[256 + u];

  // per-lane A-read base (bytes); hoisted, loop-invariant h-store address:
  // quad0 -> hi8 at u, quad1 -> lo8 at PLO+u, quads 2,3 -> dump (never read)
  const int ib = (hl ? PLO : 0) + quad * 16;
  const int haddr = (quad == 0) ? u
                  : (quad == 1) ? (PLO + u)
                                : (320 + ((L & 31) << 1));
  const bool q1 = (quad == 1);

  float hprev = 0.f;   // h[u], replicated across quads (identical math)

  // persistent zero C-operand: MFMAs write fresh dests (D != C), so no
  // per-step accumulator zeroing movs are needed.
  int4v zero4 = {0, 0, 0, 0};

  __syncthreads();

#define MI(A, B, C) __builtin_amdgcn_mfma_i32_16x16x64_i8(A, B, C, 0, 0, 0)

  // One step. h lives as i8 hi/lo: h*127 ~ hi8 + lo8/254 (exact i32 dots,
  // float recon). r's MFMAs first (needed by n's tanh), z last (needed only
  // at the final blend). Only accum regs [0],[1] are read (reg0 = even C-row
  // = hi-dot, reg1 = odd C-row = lo-dot; row = 4*quad + reg).
#define STEP(RD, WR, XT)                                                       \
  {                                                                            \
    const float xt = (XT);                                                     \
    const int4v Ai0 = *(const int4v*)&hq[RD][ib];                              \
    const int4v Ai1 = *(const int4v*)&hq[RD][ib + 64];                         \
    const float sr = fmaf(xt, wir, bcr);                                       \
    const float sz = fmaf(xt, wiz, bcz);                                       \
    const float in_s = fmaf(xt, win, bin_);                                    \
    int4v cr = MI(Ai0, Wr[0], zero4);                                          \
    cr = MI(Ai1, Wr[1], cr);                                                   \
    int4v ca = MI(Ai0, Wnh[0], zero4);                                         \
    ca = MI(Ai1, Wnh[1], ca);                                                  \
    int4v cb = MI(Ai0, Wnl[0], zero4);                                         \
    cb = MI(Ai1, Wnl[1], cb);                                                  \
    int4v cz = MI(Ai0, Wz[0], zero4);                                          \
    cz = MI(Ai1, Wz[1], cz);                                                   \
    const float crf = fmaf((float)cr[1], INV254, (float)cr[0]);                \
    const float r = __builtin_amdgcn_rcpf(                                     \
        1.f + __builtin_amdgcn_exp2f(fmaf(crf, kr, sr)));                      \
    const int tmid = ca[1] + cb[0];                                            \
    float nf = fmaf((float)tmid, INV254, (float)ca[0]);                        \
    nf = fmaf((float)cb[1], INV254SQ, nf);                                     \
    const float czf = fmaf((float)cz[1], INV254, (float)cz[0]);                \
    const float z = __builtin_amdgcn_rcpf(                                     \
        1.f + __builtin_amdgcn_exp2f(fmaf(czf, kz, sz)));                      \
    const float e =                                                            \
        __builtin_amdgcn_exp2f(fmaf(r, fmaf(nf, kn, bhn_s), in_s));            \
    const float nn = (1.f - e) * __builtin_amdgcn_rcpf(1.f + e);               \
    hprev = fmaf(z, hprev - nn, nn);                                           \
    const float hsc = hprev * 127.f;                                           \
    const int hi8 = __float2int_rn(hsc);                                       \
    const int lo8 = __float2int_rn((hsc - (float)hi8) * 254.f);                \
    hq[WR][haddr] = (char)(q1 ? lo8 : hi8);                                    \
    __syncthreads();                                                           \
  }

  float x0 = xs[0], x1 = xs[1];
  for (int s = 0; s < SEQ; s += 2) {
    const float2 xnext = *(const float2*)&xs[s + 2];  // LDS prefetch, 1 b64
    STEP(0, 1, x0);
    STEP(1, 0, x1);
    x0 = xnext.x;
    x1 = xnext.y;
  }
#undef STEP
#undef MI

  // epilogue: out[b] = relu(h_T) . w_fc + b_fc   (hprev is exact f32)
  float v = (quad == 0) ? fmaxf(hprev, 0.f) * w_fc[u] : 0.f;
#pragma unroll
  for (int off = 1; off < 64; off <<= 1) v += __shfl_xor(v, off);
  if (L == 0) red[w] = v;
  __syncthreads();
  if (t == 0) {
    float sum = 0.f;
#pragma unroll
    for (int k = 0; k < 8; ++k) sum += red[k];
    out[b] = sum + b_fc[0];
  }
}

extern "C" void kernel_launch(void* const* d_in, const int* in_sizes, int n_in,
                              void* d_out, int out_size, void* d_ws, size_t ws_size,
                              hipStream_t stream) {
  const float* x    = (const float*)d_in[0];
  const float* w_ih = (const float*)d_in[1];
  const float* w_hh = (const float*)d_in[2];
  const float* b_ih = (const float*)d_in[3];
  const float* b_hh = (const float*)d_in[4];
  const float* w_fc = (const float*)d_in[5];
  const float* b_fc = (const float*)d_in[6];
  gru_kernel<<<256, NT, 0, stream>>>(x, w_ih, w_hh, b_ih, b_hh, w_fc, b_fc,
                                     (float*)d_out);
}

// Round 9
// 344.565 us; speedup vs baseline: 1.3523x; 1.1379x over previous
//
#include <hip/hip_runtime.h>

#define SEQ 1024
#define NT 512   // 8 waves; wave w owns units [16w,16w+16) for r,z,n

typedef int int4v __attribute__((ext_vector_type(4)));  // i8 MFMA frags/accum

// i8 h buffer (bytes): hi8 at [0..127], lo8 at [192..319], dump at [320..383].
// Read addrs per b128: 8 distinct (parity x quad), spanning all 32 banks once
// (PLO=192 -> word 48 -> bank 16), 8-lane broadcast each: conflict-free.
#define PLO  192
#define QBUF 384

#define NLOG2E  (-1.4426950408889634f)   // -log2(e): sigmoid via exp2
#define N2LOG2E (-2.8853900817779268f)   // -2*log2(e): tanh via exp2
#define INV254   (0.003937007874015748f)

__global__ __launch_bounds__(NT, 2)
void gru_kernel(const float* __restrict__ x,     // [B, S, 1]
                const float* __restrict__ w_ih,  // [3H, 1]
                const float* __restrict__ w_hh,  // [3H, H]
                const float* __restrict__ b_ih,  // [3H]
                const float* __restrict__ b_hh,  // [3H]
                const float* __restrict__ w_fc,  // [1, H]
                const float* __restrict__ b_fc,  // [1]
                float* __restrict__ out)         // [B, 1]
{
  __shared__ __align__(8) float xs[SEQ + 2];
  __shared__ __align__(16) char hq[2][QBUF];
  __shared__ float red[8];

  const int t = threadIdx.x;
  const int b = blockIdx.x;
  const int w = t >> 6;          // wave 0..7
  const int L = t & 63;          // lane
  const int n = L & 15;          // MFMA col (unit) == A-row
  const int quad = L >> 4;       // k-slice / C-row group
  const int u = 16 * w + n;      // hidden unit
  const int hl = n & 1;          // A-row parity: even rows = hi8, odd = lo8

  // stage x[b,:] (coalesced); pad 2 zeros for the register prefetch
  const float* xrow = x + (size_t)b * SEQ;
  for (int i = t; i < SEQ + 2; i += NT) xs[i] = (i < SEQ) ? xrow[i] : 0.f;
  if (t < QBUF) hq[0][t] = 0;

  // ---- weight quantization (one-time) ----
  // Lane (n,quad) holds W[k = kt*64 + quad*16 + i][col=n], kt in {0,1}.
  // All three gates: single i8, per-row scale 126/rowmax. h itself is dual
  // (hi8 + lo8/254), so the h-representation error stays ~3e-5; the weight
  // quant error (~rowmax/252) is the accepted noise source (r,z carried it
  // since R5 at absmax 0.0).
  int4v Wr[2], Wz[2], Wn[2];
  float kr, kz, kn;
#pragma unroll
  for (int g = 0; g < 3; ++g) {
    const float* row = w_hh + (size_t)(g * 128 + u) * 128;
    float wv[32];
    float m = 0.f;
#pragma unroll
    for (int kt = 0; kt < 2; ++kt)
#pragma unroll
      for (int i = 0; i < 16; ++i) {
        const float v = row[kt * 64 + quad * 16 + i];
        wv[kt * 16 + i] = v;
        m = fmaxf(m, fabsf(v));
      }
    m = fmaxf(m, __shfl_xor(m, 16));   // rowmax across the 4 quads
    m = fmaxf(m, __shfl_xor(m, 32));
    const float Sw = 126.f / m;
#pragma unroll
    for (int kt = 0; kt < 2; ++kt) {
      int ph[4] = {0, 0, 0, 0};
#pragma unroll
      for (int i = 0; i < 16; ++i) {
        const int qh = __float2int_rn(wv[kt * 16 + i] * Sw);
        ph[i >> 2] |= (qh & 255) << (8 * (i & 3));
      }
      const int4v vh = {ph[0], ph[1], ph[2], ph[3]};
      if (g == 0) Wr[kt] = vh;
      else if (g == 1) Wz[kt] = vh;
      else Wn[kt] = vh;
    }
    const float ksc = m / 16002.f;     // m/(126*127)
    if (g == 0) kr = NLOG2E * ksc;
    else if (g == 1) kz = NLOG2E * ksc;
    else kn = N2LOG2E * ksc;
  }

  // pre-scaled per-unit scalars (input preact + biases folded into seeds)
  const float bcr = NLOG2E * (b_ih[u] + b_hh[u]);
  const float bcz = NLOG2E * (b_ih[128 + u] + b_hh[128 + u]);
  const float bin_ = N2LOG2E * b_ih[256 + u];
  const float bhn_s = N2LOG2E * b_hh[256 + u];
  const float wir = NLOG2E * w_ih[u];
  const float wiz = NLOG2E * w_ih[128 + u];
  const float win = N2LOG2E * w_ih[256 + u];

  // per-lane A-read base (bytes); hoisted, loop-invariant h-store address:
  // quad0 -> hi8 at u, quad1 -> lo8 at PLO+u, quads 2,3 -> dump (never read)
  const int ib = (hl ? PLO : 0) + quad * 16;
  const int haddr = (quad == 0) ? u
                  : (quad == 1) ? (PLO + u)
                                : (320 + ((L & 31) << 1));
  const bool q1 = (quad == 1);

  float hprev = 0.f;   // h[u], replicated across quads (identical math)

  // persistent zero C-operand: MFMAs write fresh dests (D != C), so no
  // per-step accumulator zeroing movs are needed.
  int4v zero4 = {0, 0, 0, 0};

  __syncthreads();

#define MI(A, B, C) __builtin_amdgcn_mfma_i32_16x16x64_i8(A, B, C, 0, 0, 0)

  // One step. h lives as i8 hi/lo: h*127 ~ hi8 + lo8/254 (exact i32 dots,
  // float recon). MFMA order r, z, n: both sigmoids retire under the n-gate
  // issue; the post-last-MFMA serial chain is just the n-tail + blend +
  // quantize. Only accum regs [0],[1] are read (reg0 = even C-row = hi-dot,
  // reg1 = odd C-row = lo-dot; row = 4*quad + reg).
#define STEP(RD, WR, XT)                                                       \
  {                                                                            \
    const float xt = (XT);                                                     \
    const int4v Ai0 = *(const int4v*)&hq[RD][ib];                              \
    const int4v Ai1 = *(const int4v*)&hq[RD][ib + 64];                         \
    const float sr = fmaf(xt, wir, bcr);                                       \
    const float sz = fmaf(xt, wiz, bcz);                                       \
    const float in_s = fmaf(xt, win, bin_);                                    \
    int4v cr = MI(Ai0, Wr[0], zero4);                                          \
    cr = MI(Ai1, Wr[1], cr);                                                   \
    int4v cz = MI(Ai0, Wz[0], zero4);                                          \
    cz = MI(Ai1, Wz[1], cz);                                                   \
    int4v ca = MI(Ai0, Wn[0], zero4);                                          \
    ca = MI(Ai1, Wn[1], ca);                                                   \
    const float crf = fmaf((float)cr[1], INV254, (float)cr[0]);                \
    const float r = __builtin_amdgcn_rcpf(                                     \
        1.f + __builtin_amdgcn_exp2f(fmaf(crf, kr, sr)));                      \
    const float czf = fmaf((float)cz[1], INV254, (float)cz[0]);                \
    const float z = __builtin_amdgcn_rcpf(                                     \
        1.f + __builtin_amdgcn_exp2f(fmaf(czf, kz, sz)));                      \
    const float nf = fmaf((float)ca[1], INV254, (float)ca[0]);                 \
    const float e =                                                            \
        __builtin_amdgcn_exp2f(fmaf(r, fmaf(nf, kn, bhn_s), in_s));            \
    const float nn = (1.f - e) * __builtin_amdgcn_rcpf(1.f + e);               \
    hprev = fmaf(z, hprev - nn, nn);                                           \
    const float hsc = hprev * 127.f;                                           \
    const int hi8 = __float2int_rn(hsc);                                       \
    const int lo8 = __float2int_rn((hsc - (float)hi8) * 254.f);                \
    hq[WR][haddr] = (char)(q1 ? lo8 : hi8);                                    \
    __syncthreads();                                                           \
  }

  float x0 = xs[0], x1 = xs[1];
  for (int s = 0; s < SEQ; s += 2) {
    const float2 xnext = *(const float2*)&xs[s + 2];  // LDS prefetch, 1 b64
    STEP(0, 1, x0);
    STEP(1, 0, x1);
    x0 = xnext.x;
    x1 = xnext.y;
  }
#undef STEP
#undef MI

  // epilogue: out[b] = relu(h_T) . w_fc + b_fc   (hprev is exact f32)
  float v = (quad == 0) ? fmaxf(hprev, 0.f) * w_fc[u] : 0.f;
#pragma unroll
  for (int off = 1; off < 64; off <<= 1) v += __shfl_xor(v, off);
  if (L == 0) red[w] = v;
  __syncthreads();
  if (t == 0) {
    float sum = 0.f;
#pragma unroll
    for (int k = 0; k < 8; ++k) sum += red[k];
    out[b] = sum + b_fc[0];
  }
}

extern "C" void kernel_launch(void* const* d_in, const int* in_sizes, int n_in,
                              void* d_out, int out_size, void* d_ws, size_t ws_size,
                              hipStream_t stream) {
  const float* x    = (const float*)d_in[0];
  const float* w_ih = (const float*)d_in[1];
  const float* w_hh = (const float*)d_in[2];
  const float* b_ih = (const float*)d_in[3];
  const float* b_hh = (const float*)d_in[4];
  const float* w_fc = (const float*)d_in[5];
  const float* b_fc = (const float*)d_in[6];
  gru_kernel<<<256, NT, 0, stream>>>(x, w_ih, w_hh, b_ih, b_hh, w_fc, b_fc,
                                     (float*)d_out);
}

// Round 10
// 330.913 us; speedup vs baseline: 1.4081x; 1.0413x over previous
//
#include <hip/hip_runtime.h>

#define SEQ 1024
#define NT 512   // 8 waves; wave w owns units [16w,16w+16) for r,z,n

typedef int int4v __attribute__((ext_vector_type(4)));  // i8 MFMA frags/accum

// i8 h buffer (bytes): hi8 at [0..127], dump at [256..319].
// A-reads (b128): 4 distinct addrs x 16-lane broadcast, banks 0-15 (Ai0)
// and 16-31 (Ai1): conflict-free.
#define QBUF 384

#define NLOG2E  (-1.4426950408889634f)   // -log2(e): sigmoid via exp2
#define N2LOG2E (-2.8853900817779268f)   // -2*log2(e): tanh via exp2

__global__ __launch_bounds__(NT, 2)
void gru_kernel(const float* __restrict__ x,     // [B, S, 1]
                const float* __restrict__ w_ih,  // [3H, 1]
                const float* __restrict__ w_hh,  // [3H, H]
                const float* __restrict__ b_ih,  // [3H]
                const float* __restrict__ b_hh,  // [3H]
                const float* __restrict__ w_fc,  // [1, H]
                const float* __restrict__ b_fc,  // [1]
                float* __restrict__ out)         // [B, 1]
{
  __shared__ __align__(8) float xs[SEQ + 2];
  __shared__ __align__(16) char hq[2][QBUF];
  __shared__ float red[8];

  const int t = threadIdx.x;
  const int b = blockIdx.x;
  const int w = t >> 6;          // wave 0..7
  const int L = t & 63;          // lane
  const int n = L & 15;          // MFMA col (unit) == A-row
  const int quad = L >> 4;       // k-slice / C-row group
  const int u = 16 * w + n;      // hidden unit

  // stage x[b,:] (coalesced); pad 2 zeros for the register prefetch
  const float* xrow = x + (size_t)b * SEQ;
  for (int i = t; i < SEQ + 2; i += NT) xs[i] = (i < SEQ) ? xrow[i] : 0.f;
  if (t < QBUF) hq[0][t] = 0;

  // ---- weight quantization (one-time) ----
  // Lane (n,quad) holds W[k = kt*64 + quad*16 + i][col=n], kt in {0,1}.
  // All three gates: single i8, per-row scale 126/rowmax. h is single i8
  // (h*127 rounded): h-quant noise ~1.3e-3 preact RMS, same order as the
  // weight-quant noise that measured +1 fp16 ulp in R8.
  int4v Wr[2], Wz[2], Wn[2];
  float kr, kz, kn;
#pragma unroll
  for (int g = 0; g < 3; ++g) {
    const float* row = w_hh + (size_t)(g * 128 + u) * 128;
    float wv[32];
    float m = 0.f;
#pragma unroll
    for (int kt = 0; kt < 2; ++kt)
#pragma unroll
      for (int i = 0; i < 16; ++i) {
        const float v = row[kt * 64 + quad * 16 + i];
        wv[kt * 16 + i] = v;
        m = fmaxf(m, fabsf(v));
      }
    m = fmaxf(m, __shfl_xor(m, 16));   // rowmax across the 4 quads
    m = fmaxf(m, __shfl_xor(m, 32));
    const float Sw = 126.f / m;
#pragma unroll
    for (int kt = 0; kt < 2; ++kt) {
      int ph[4] = {0, 0, 0, 0};
#pragma unroll
      for (int i = 0; i < 16; ++i) {
        const int qh = __float2int_rn(wv[kt * 16 + i] * Sw);
        ph[i >> 2] |= (qh & 255) << (8 * (i & 3));
      }
      const int4v vh = {ph[0], ph[1], ph[2], ph[3]};
      if (g == 0) Wr[kt] = vh;
      else if (g == 1) Wz[kt] = vh;
      else Wn[kt] = vh;
    }
    const float ksc = m / 16002.f;     // m/(126*127)
    if (g == 0) kr = NLOG2E * ksc;
    else if (g == 1) kz = NLOG2E * ksc;
    else kn = N2LOG2E * ksc;
  }

  // pre-scaled per-unit scalars (input preact + biases folded into seeds)
  const float bcr = NLOG2E * (b_ih[u] + b_hh[u]);
  const float bcz = NLOG2E * (b_ih[128 + u] + b_hh[128 + u]);
  const float bin_ = N2LOG2E * b_ih[256 + u];
  const float bhn_s = N2LOG2E * b_hh[256 + u];
  const float wir = NLOG2E * w_ih[u];
  const float wiz = NLOG2E * w_ih[128 + u];
  const float win = N2LOG2E * w_ih[256 + u];

  // per-lane A-read base (bytes); hoisted, loop-invariant h-store address:
  // quad0 -> hi8 at u; quads 1,2,3 -> dump at 256+L (never read, 0 conflicts)
  const int ib = quad * 16;
  const int haddr = (quad == 0) ? u : (256 + L);

  float hprev = 0.f;   // h[u], replicated across quads (identical math)

  // persistent zero C-operand: MFMAs write fresh dests (D != C), so no
  // per-step accumulator zeroing movs are needed.
  int4v zero4 = {0, 0, 0, 0};

  __syncthreads();

#define MI(A, B, C) __builtin_amdgcn_mfma_i32_16x16x64_i8(A, B, C, 0, 0, 0)

  // One step. h lives as single i8 (h*127): all A-rows read hi8, so every
  // C row is the same dot -> use reg [0] only, no hi/lo recon. MFMA order
  // r, z, n: both sigmoids retire under the n-gate issue; the post-last-MFMA
  // serial chain is n-tail + blend + one cvt.
#define STEP(RD, WR, XT)                                                       \
  {                                                                            \
    const float xt = (XT);                                                     \
    const int4v Ai0 = *(const int4v*)&hq[RD][ib];                              \
    const int4v Ai1 = *(const int4v*)&hq[RD][ib + 64];                         \
    const float sr = fmaf(xt, wir, bcr);                                       \
    const float sz = fmaf(xt, wiz, bcz);                                       \
    const float in_s = fmaf(xt, win, bin_);                                    \
    int4v cr = MI(Ai0, Wr[0], zero4);                                          \
    cr = MI(Ai1, Wr[1], cr);                                                   \
    int4v cz = MI(Ai0, Wz[0], zero4);                                          \
    cz = MI(Ai1, Wz[1], cz);                                                   \
    int4v ca = MI(Ai0, Wn[0], zero4);                                          \
    ca = MI(Ai1, Wn[1], ca);                                                   \
    const float r = __builtin_amdgcn_rcpf(                                     \
        1.f + __builtin_amdgcn_exp2f(fmaf((float)cr[0], kr, sr)));             \
    const float z = __builtin_amdgcn_rcpf(                                     \
        1.f + __builtin_amdgcn_exp2f(fmaf((float)cz[0], kz, sz)));             \
    const float z127 = z * 127.f;                                              \
    const float e = __builtin_amdgcn_exp2f(                                    \
        fmaf(r, fmaf((float)ca[0], kn, bhn_s), in_s));                         \
    const float rcpv = __builtin_amdgcn_rcpf(1.f + e);                         \
    const float nn = fmaf(2.f, rcpv, -1.f);        /* tanh = 2/(1+e)-1 */      \
    const float nn127 = fmaf(254.f, rcpv, -127.f);                             \
    const float d = hprev - nn;                                                \
    hprev = fmaf(z, d, nn);                                                    \
    const float hsc = fmaf(z127, d, nn127);        /* = hprev*127 */           \
    const int hi8 = __float2int_rn(hsc);                                       \
    hq[WR][haddr] = (char)hi8;                                                 \
    __syncthreads();                                                           \
  }

  float x0 = xs[0], x1 = xs[1];
  for (int s = 0; s < SEQ; s += 2) {
    const float2 xnext = *(const float2*)&xs[s + 2];  // LDS prefetch, 1 b64
    STEP(0, 1, x0);
    STEP(1, 0, x1);
    x0 = xnext.x;
    x1 = xnext.y;
  }
#undef STEP
#undef MI

  // epilogue: out[b] = relu(h_T) . w_fc + b_fc   (hprev is exact f32)
  float v = (quad == 0) ? fmaxf(hprev, 0.f) * w_fc[u] : 0.f;
#pragma unroll
  for (int off = 1; off < 64; off <<= 1) v += __shfl_xor(v, off);
  if (L == 0) red[w] = v;
  __syncthreads();
  if (t == 0) {
    float sum = 0.f;
#pragma unroll
    for (int k = 0; k < 8; ++k) sum += red[k];
    out[b] = sum + b_fc[0];
  }
}

extern "C" void kernel_launch(void* const* d_in, const int* in_sizes, int n_in,
                              void* d_out, int out_size, void* d_ws, size_t ws_size,
                              hipStream_t stream) {
  const float* x    = (const float*)d_in[0];
  const float* w_ih = (const float*)d_in[1];
  const float* w_hh = (const float*)d_in[2];
  const float* b_ih = (const float*)d_in[3];
  const float* b_hh = (const float*)d_in[4];
  const float* w_fc = (const float*)d_in[5];
  const float* b_fc = (const float*)d_in[6];
  gru_kernel<<<256, NT, 0, stream>>>(x, w_ih, w_hh, b_ih, b_hh, w_fc, b_fc,
                                     (float*)d_out);
}

// Round 11
// 304.867 us; speedup vs baseline: 1.5284x; 1.0854x over previous
//
#include <hip/hip_runtime.h>

#define SEQ 1024
#define NT 512   // 8 waves; wave w owns units [16w,16w+16) for r,z,n

typedef int int4v __attribute__((ext_vector_type(4)));  // i8 MFMA frags/accum

// i8 h buffer (bytes): hi8 at [0..127], dump at [256..319].
// A-reads (b128): 4 distinct addrs x 16-lane broadcast, banks 0-15 (Ai0)
// and 16-31 (Ai1): conflict-free.
#define QBUF 384

#define NLOG2E  (-1.4426950408889634f)   // -log2(e): sigmoid via exp2
#define N2LOG2E (-2.8853900817779268f)   // -2*log2(e): tanh via exp2

__global__ __launch_bounds__(NT, 2)
void gru_kernel(const float* __restrict__ x,     // [B, S, 1]
                const float* __restrict__ w_ih,  // [3H, 1]
                const float* __restrict__ w_hh,  // [3H, H]
                const float* __restrict__ b_ih,  // [3H]
                const float* __restrict__ b_hh,  // [3H]
                const float* __restrict__ w_fc,  // [1, H]
                const float* __restrict__ b_fc,  // [1]
                float* __restrict__ out)         // [B, 1]
{
  __shared__ __align__(8) float xs[SEQ + 2];
  __shared__ __align__(16) char hq[2][QBUF];
  __shared__ float red[8];

  const int t = threadIdx.x;
  const int b = blockIdx.x;
  const int w = t >> 6;          // wave 0..7
  const int L = t & 63;          // lane
  const int n = L & 15;          // MFMA col (unit) == A-row
  const int quad = L >> 4;       // k-slice / C-row group
  const int u = 16 * w + n;      // hidden unit

  // stage x[b,:] (coalesced); pad 2 zeros for the register prefetch
  const float* xrow = x + (size_t)b * SEQ;
  for (int i = t; i < SEQ + 2; i += NT) xs[i] = (i < SEQ) ? xrow[i] : 0.f;
  if (t < QBUF) hq[0][t] = 0;

  // ---- weight quantization (one-time) ----
  // Lane (n,quad) holds W[k = kt*64 + quad*16 + i][col=n], kt in {0,1}.
  // All three gates: single i8, per-row scale 126/rowmax. h is single i8
  // (h*127 rounded).
  int4v Wr[2], Wz[2], Wn[2];
  float kr, kz, kn;
#pragma unroll
  for (int g = 0; g < 3; ++g) {
    const float* row = w_hh + (size_t)(g * 128 + u) * 128;
    float wv[32];
    float m = 0.f;
#pragma unroll
    for (int kt = 0; kt < 2; ++kt)
#pragma unroll
      for (int i = 0; i < 16; ++i) {
        const float v = row[kt * 64 + quad * 16 + i];
        wv[kt * 16 + i] = v;
        m = fmaxf(m, fabsf(v));
      }
    m = fmaxf(m, __shfl_xor(m, 16));   // rowmax across the 4 quads
    m = fmaxf(m, __shfl_xor(m, 32));
    const float Sw = 126.f / m;
#pragma unroll
    for (int kt = 0; kt < 2; ++kt) {
      int ph[4] = {0, 0, 0, 0};
#pragma unroll
      for (int i = 0; i < 16; ++i) {
        const int qh = __float2int_rn(wv[kt * 16 + i] * Sw);
        ph[i >> 2] |= (qh & 255) << (8 * (i & 3));
      }
      const int4v vh = {ph[0], ph[1], ph[2], ph[3]};
      if (g == 0) Wr[kt] = vh;
      else if (g == 1) Wz[kt] = vh;
      else Wn[kt] = vh;
    }
    const float ksc = m / 16002.f;     // m/(126*127)
    if (g == 0) kr = NLOG2E * ksc;
    else if (g == 1) kz = NLOG2E * ksc;
    else kn = N2LOG2E * ksc;
  }

  // pre-scaled per-unit scalars (input preact + biases folded into seeds)
  const float bcr = NLOG2E * (b_ih[u] + b_hh[u]);
  const float bcz = NLOG2E * (b_ih[128 + u] + b_hh[128 + u]);
  const float bin_ = N2LOG2E * b_ih[256 + u];
  const float bhn_s = N2LOG2E * b_hh[256 + u];
  const float wir = NLOG2E * w_ih[u];
  const float wiz = NLOG2E * w_ih[128 + u];
  const float win = N2LOG2E * w_ih[256 + u];

  // per-lane A-read base (bytes); hoisted, loop-invariant h-store address:
  // quad0 -> hi8 at u; quads 1,2,3 -> dump at 256+L (never read)
  const int ib = quad * 16;
  const int haddr = (quad == 0) ? u : (256 + L);

  // h is carried ONLY as h127 = h * 127 (f32). The store is round(h127);
  // the epilogue multiplies by 1/127 once. Same recurrence, scaled.
  float h127 = 0.f;

  // persistent zero C-operand: MFMAs write fresh dests (D != C), so no
  // per-step accumulator zeroing movs are needed.
  int4v zero4 = {0, 0, 0, 0};

  __syncthreads();

#define MI(A, B, C) __builtin_amdgcn_mfma_i32_16x16x64_i8(A, B, C, 0, 0, 0)

  // One step. MFMA order r, n, z = dot-consumption order: r feeds the
  // n-preact (longest chain, starts earliest), z is needed only at the
  // final blend (its short sigmoid chain hides under n's exp2/rcp).
  // Only accum reg [0] is read (all C rows identical: A-rows replicated).
#define STEP(RD, WR, XT)                                                       \
  {                                                                            \
    const float xt = (XT);                                                     \
    const int4v Ai0 = *(const int4v*)&hq[RD][ib];                              \
    const int4v Ai1 = *(const int4v*)&hq[RD][ib + 64];                         \
    const float sr = fmaf(xt, wir, bcr);                                       \
    const float sz = fmaf(xt, wiz, bcz);                                       \
    const float in_s = fmaf(xt, win, bin_);                                    \
    int4v cr = MI(Ai0, Wr[0], zero4);                                          \
    cr = MI(Ai1, Wr[1], cr);                                                   \
    int4v ca = MI(Ai0, Wn[0], zero4);                                          \
    ca = MI(Ai1, Wn[1], ca);                                                   \
    int4v cz = MI(Ai0, Wz[0], zero4);                                          \
    cz = MI(Ai1, Wz[1], cz);                                                   \
    const float r = __builtin_amdgcn_rcpf(                                     \
        1.f + __builtin_amdgcn_exp2f(fmaf((float)cr[0], kr, sr)));             \
    const float pn = fmaf((float)ca[0], kn, bhn_s);                            \
    const float e = __builtin_amdgcn_exp2f(fmaf(r, pn, in_s));                 \
    const float rcpv = __builtin_amdgcn_rcpf(1.f + e);                         \
    const float nn127 = fmaf(254.f, rcpv, -127.f);   /* tanh*127 */            \
    const float z = __builtin_amdgcn_rcpf(                                     \
        1.f + __builtin_amdgcn_exp2f(fmaf((float)cz[0], kz, sz)));             \
    h127 = fmaf(z, h127 - nn127, nn127);                                       \
    const int hi8 = __float2int_rn(h127);                                      \
    hq[WR][haddr] = (char)hi8;                                                 \
    __syncthreads();                                                           \
  }

  float x0 = xs[0], x1 = xs[1];
  for (int s = 0; s < SEQ; s += 2) {
    const float2 xnext = *(const float2*)&xs[s + 2];  // LDS prefetch, 1 b64
    STEP(0, 1, x0);
    STEP(1, 0, x1);
    x0 = xnext.x;
    x1 = xnext.y;
  }
#undef STEP
#undef MI

  // epilogue: out[b] = relu(h_T) . w_fc + b_fc   (h = h127/127, exact f32)
  float v = (quad == 0)
                ? fmaxf(h127 * 0.007874015748031496f, 0.f) * w_fc[u]
                : 0.f;
#pragma unroll
  for (int off = 1; off < 64; off <<= 1) v += __shfl_xor(v, off);
  if (L == 0) red[w] = v;
  __syncthreads();
  if (t == 0) {
    float sum = 0.f;
#pragma unroll
    for (int k = 0; k < 8; ++k) sum += red[k];
    out[b] = sum + b_fc[0];
  }
}

extern "C" void kernel_launch(void* const* d_in, const int* in_sizes, int n_in,
                              void* d_out, int out_size, void* d_ws, size_t ws_size,
                              hipStream_t stream) {
  const float* x    = (const float*)d_in[0];
  const float* w_ih = (const float*)d_in[1];
  const float* w_hh = (const float*)d_in[2];
  const float* b_ih = (const float*)d_in[3];
  const float* b_hh = (const float*)d_in[4];
  const float* w_fc = (const float*)d_in[5];
  const float* b_fc = (const float*)d_in[6];
  gru_kernel<<<256, NT, 0, stream>>>(x, w_ih, w_hh, b_ih, b_hh, w_fc, b_fc,
                                     (float*)d_out);
}